// Round 4
// baseline (241.928 us; speedup 1.0000x reference)
//
#include <hip/hip_runtime.h>
#include <math.h>

#define EPS 1e-05

static constexpr int BLOCK  = 256;
static constexpr int BPB    = 432;   // blocks per batch
static constexpr int KPT    = 16;    // float4s per thread per stream (432*256*16 = 192^3/4)
static constexpr int GRP    = 4;     // float4s per pipeline stage per stream
static constexpr int NBATCH = 4;
static constexpr long long NPB = 192LL * 192LL * 192LL; // 7,077,888 elems/batch

typedef float v4f __attribute__((ext_vector_type(4)));

__device__ __forceinline__ double wave_reduce(double v) {
    #pragma unroll
    for (int off = 32; off > 0; off >>= 1)
        v += __shfl_down(v, off, 64);
    return v;
}

__global__ __launch_bounds__(BLOCK, 4) void ncc_partial(
    const float* __restrict__ y_pred, const float* __restrict__ y_true,
    double* __restrict__ part)
{
    const int b  = blockIdx.y;
    const int bx = blockIdx.x;
    const v4f* __restrict__ I4 = (const v4f*)(y_true + (long long)b * NPB);
    const v4f* __restrict__ J4 = (const v4f*)(y_pred + (long long)b * NPB);

    // 32-bit indexing: max float4 index 1,769,471 -> byte offset < 28.4 MB.
    const unsigned base = (unsigned)bx * (BLOCK * KPT) + threadIdx.x;

    double sI = 0.0, sJ = 0.0, sI2 = 0.0, sJ2 = 0.0, sIJ = 0.0;

    // Double-buffered software pipeline: 8 loads (32 VGPRs) per buffer,
    // group g+1's loads issue before group g's math.
    v4f a[2][GRP], c[2][GRP];
    #pragma unroll
    for (int u = 0; u < GRP; ++u) {
        a[0][u] = I4[base + u * BLOCK];
        c[0][u] = J4[base + u * BLOCK];
    }
    #pragma unroll
    for (int g = 0; g < KPT / GRP; ++g) {
        const int cur = g & 1, nxt = cur ^ 1;
        if (g < KPT / GRP - 1) {
            const unsigned o = base + (unsigned)(g + 1) * GRP * BLOCK;
            #pragma unroll
            for (int u = 0; u < GRP; ++u) {
                a[nxt][u] = I4[o + u * BLOCK];
                c[nxt][u] = J4[o + u * BLOCK];
            }
        }
        #pragma unroll
        for (int u = 0; u < GRP; ++u) {
            const v4f av = a[cur][u], cv = c[cur][u];
            // f32 per-group math (cc error ~1e-10, threshold 4.1e-6), f64 accumulate.
            float gI  = (av.x + av.y) + (av.z + av.w);
            float gJ  = (cv.x + cv.y) + (cv.z + cv.w);
            float gI2 = fmaf(av.x, av.x, fmaf(av.y, av.y, fmaf(av.z, av.z, av.w * av.w)));
            float gJ2 = fmaf(cv.x, cv.x, fmaf(cv.y, cv.y, fmaf(cv.z, cv.z, cv.w * cv.w)));
            float gIJ = fmaf(av.x, cv.x, fmaf(av.y, cv.y, fmaf(av.z, cv.z, av.w * cv.w)));
            sI  += (double)gI;
            sJ  += (double)gJ;
            sI2 += (double)gI2;
            sJ2 += (double)gJ2;
            sIJ += (double)gIJ;
        }
    }

    sI  = wave_reduce(sI);
    sJ  = wave_reduce(sJ);
    sI2 = wave_reduce(sI2);
    sJ2 = wave_reduce(sJ2);
    sIJ = wave_reduce(sIJ);

    __shared__ double lds[BLOCK / 64][5];
    const int wave = threadIdx.x >> 6;
    const int lane = threadIdx.x & 63;
    if (lane == 0) {
        lds[wave][0] = sI;  lds[wave][1] = sJ;
        lds[wave][2] = sI2; lds[wave][3] = sJ2;
        lds[wave][4] = sIJ;
    }
    __syncthreads();
    if (threadIdx.x == 0) {
        double* p = part + ((long long)b * BPB + bx) * 5;
        #pragma unroll
        for (int k = 0; k < 5; ++k)
            p[k] = ((lds[0][k] + lds[1][k]) + (lds[2][k] + lds[3][k]));
    }
}

__global__ __launch_bounds__(BLOCK) void ncc_final(
    const double* __restrict__ part, float* __restrict__ out)
{
    const int b = blockIdx.x;
    double s[5] = {0.0, 0.0, 0.0, 0.0, 0.0};
    for (int i = threadIdx.x; i < BPB; i += BLOCK) {
        const double* p = part + ((long long)b * BPB + i) * 5;
        #pragma unroll
        for (int k = 0; k < 5; ++k) s[k] += p[k];
    }
    #pragma unroll
    for (int k = 0; k < 5; ++k) s[k] = wave_reduce(s[k]);

    __shared__ double lds[BLOCK / 64][5];
    const int wave = threadIdx.x >> 6;
    const int lane = threadIdx.x & 63;
    if (lane == 0) {
        #pragma unroll
        for (int k = 0; k < 5; ++k) lds[wave][k] = s[k];
    }
    __syncthreads();
    if (threadIdx.x == 0) {
        double I_sum  = (lds[0][0] + lds[1][0]) + (lds[2][0] + lds[3][0]);
        double J_sum  = (lds[0][1] + lds[1][1]) + (lds[2][1] + lds[3][1]);
        double I2_sum = (lds[0][2] + lds[1][2]) + (lds[2][2] + lds[3][2]);
        double J2_sum = (lds[0][3] + lds[1][3]) + (lds[2][3] + lds[3][3]);
        double IJ_sum = (lds[0][4] + lds[1][4]) + (lds[2][4] + lds[3][4]);

        const double win = (double)NPB;
        const double u_I = I_sum / win;
        const double u_J = J_sum / win;
        const double cross = IJ_sum - u_J * I_sum - u_I * J_sum + u_I * u_J * win;
        const double I_var = I2_sum - 2.0 * u_I * I_sum + u_I * u_I * win;
        const double J_var = J2_sum - 2.0 * u_J * J_sum + u_J * u_J * win;
        const double cc = cross / (sqrt(I_var) * sqrt(J_var) + EPS);
        out[b] = (float)cc;
    }
}

extern "C" void kernel_launch(void* const* d_in, const int* in_sizes, int n_in,
                              void* d_out, int out_size, void* d_ws, size_t ws_size,
                              hipStream_t stream) {
    // setup_inputs order: y_pred, y_true. reference(y_pred, y_true): Ii=y_true, Ji=y_pred.
    const float* y_pred = (const float*)d_in[0];
    const float* y_true = (const float*)d_in[1];
    float* out = (float*)d_out;
    double* part = (double*)d_ws;   // 4 * 432 * 5 * 8 B = 69 KB

    dim3 grid1(BPB, NBATCH);
    ncc_partial<<<grid1, BLOCK, 0, stream>>>(y_pred, y_true, part);
    ncc_final<<<NBATCH, BLOCK, 0, stream>>>(part, out);
}

// Round 5
// 213.009 us; speedup vs baseline: 1.1358x; 1.1358x over previous
//
#include <hip/hip_runtime.h>
#include <math.h>

#define EPS 1e-05

static constexpr int BLOCK  = 256;
static constexpr int BPB    = 256;   // blocks per batch
static constexpr int KPT    = 27;    // float4s per thread per stream (256*256*27 = 192^3/4)
static constexpr int NBATCH = 4;
static constexpr long long NPB = 192LL * 192LL * 192LL; // 7,077,888 elems/batch

typedef float v4f __attribute__((ext_vector_type(4)));

__device__ __forceinline__ double wave_reduce(double v) {
    #pragma unroll
    for (int off = 32; off > 0; off >>= 1)
        v += __shfl_down(v, off, 64);
    return v;
}

__global__ __launch_bounds__(BLOCK) void ncc_partial(
    const float* __restrict__ y_pred, const float* __restrict__ y_true,
    double* __restrict__ part)
{
    const int b  = blockIdx.y;
    const int bx = blockIdx.x;
    const v4f* __restrict__ I4 = (const v4f*)(y_true + (long long)b * NPB);
    const v4f* __restrict__ J4 = (const v4f*)(y_pred + (long long)b * NPB);

    // 32-bit indexing: max float4 index 1,769,471 -> byte offset < 28.4 MB.
    // SAME index for both streams (pairing is required for IJ_sum — R3's xor
    // decorrelation broke it; do NOT reintroduce).
    const unsigned base = (unsigned)bx * (BLOCK * KPT) + threadIdx.x;

    double sI = 0.0, sJ = 0.0, sI2 = 0.0, sJ2 = 0.0, sIJ = 0.0;
    #pragma unroll
    for (int k = 0; k < KPT; ++k) {
        // Non-temporal: streaming data, bypass cache allocation (216 MiB
        // footprint thrashes the 256 MiB L3 otherwise).
        v4f a = __builtin_nontemporal_load(I4 + base + k * BLOCK);
        v4f c = __builtin_nontemporal_load(J4 + base + k * BLOCK);
        // f32 per-group math (cc error ~1e-10 vs 4.1e-6 threshold), f64 accumulate.
        float gI  = (a.x + a.y) + (a.z + a.w);
        float gJ  = (c.x + c.y) + (c.z + c.w);
        float gI2 = fmaf(a.x, a.x, fmaf(a.y, a.y, fmaf(a.z, a.z, a.w * a.w)));
        float gJ2 = fmaf(c.x, c.x, fmaf(c.y, c.y, fmaf(c.z, c.z, c.w * c.w)));
        float gIJ = fmaf(a.x, c.x, fmaf(a.y, c.y, fmaf(a.z, c.z, a.w * c.w)));
        sI  += (double)gI;
        sJ  += (double)gJ;
        sI2 += (double)gI2;
        sJ2 += (double)gJ2;
        sIJ += (double)gIJ;
    }

    sI  = wave_reduce(sI);
    sJ  = wave_reduce(sJ);
    sI2 = wave_reduce(sI2);
    sJ2 = wave_reduce(sJ2);
    sIJ = wave_reduce(sIJ);

    __shared__ double lds[BLOCK / 64][5];
    const int wave = threadIdx.x >> 6;
    const int lane = threadIdx.x & 63;
    if (lane == 0) {
        lds[wave][0] = sI;  lds[wave][1] = sJ;
        lds[wave][2] = sI2; lds[wave][3] = sJ2;
        lds[wave][4] = sIJ;
    }
    __syncthreads();
    if (threadIdx.x == 0) {
        double* p = part + ((long long)b * BPB + bx) * 5;
        #pragma unroll
        for (int k = 0; k < 5; ++k)
            p[k] = ((lds[0][k] + lds[1][k]) + (lds[2][k] + lds[3][k]));
    }
}

__global__ __launch_bounds__(BLOCK) void ncc_final(
    const double* __restrict__ part, float* __restrict__ out)
{
    const int b = blockIdx.x;
    // One partial set per thread (BPB == BLOCK == 256).
    const double* p = part + ((long long)b * BPB + threadIdx.x) * 5;
    double s[5];
    #pragma unroll
    for (int k = 0; k < 5; ++k) s[k] = p[k];
    #pragma unroll
    for (int k = 0; k < 5; ++k) s[k] = wave_reduce(s[k]);

    __shared__ double lds[BLOCK / 64][5];
    const int wave = threadIdx.x >> 6;
    const int lane = threadIdx.x & 63;
    if (lane == 0) {
        #pragma unroll
        for (int k = 0; k < 5; ++k) lds[wave][k] = s[k];
    }
    __syncthreads();
    if (threadIdx.x == 0) {
        double I_sum  = (lds[0][0] + lds[1][0]) + (lds[2][0] + lds[3][0]);
        double J_sum  = (lds[0][1] + lds[1][1]) + (lds[2][1] + lds[3][1]);
        double I2_sum = (lds[0][2] + lds[1][2]) + (lds[2][2] + lds[3][2]);
        double J2_sum = (lds[0][3] + lds[1][3]) + (lds[2][3] + lds[3][3]);
        double IJ_sum = (lds[0][4] + lds[1][4]) + (lds[2][4] + lds[3][4]);

        const double win = (double)NPB;
        const double u_I = I_sum / win;
        const double u_J = J_sum / win;
        const double cross = IJ_sum - u_J * I_sum - u_I * J_sum + u_I * u_J * win;
        const double I_var = I2_sum - 2.0 * u_I * I_sum + u_I * u_I * win;
        const double J_var = J2_sum - 2.0 * u_J * J_sum + u_J * u_J * win;
        const double cc = cross / (sqrt(I_var) * sqrt(J_var) + EPS);
        out[b] = (float)cc;
    }
}

extern "C" void kernel_launch(void* const* d_in, const int* in_sizes, int n_in,
                              void* d_out, int out_size, void* d_ws, size_t ws_size,
                              hipStream_t stream) {
    // setup_inputs order: y_pred, y_true. reference(y_pred, y_true): Ii=y_true, Ji=y_pred.
    const float* y_pred = (const float*)d_in[0];
    const float* y_true = (const float*)d_in[1];
    float* out = (float*)d_out;
    double* part = (double*)d_ws;   // 4 * 256 * 5 * 8 B = 40 KB

    dim3 grid1(BPB, NBATCH);
    ncc_partial<<<grid1, BLOCK, 0, stream>>>(y_pred, y_true, part);
    ncc_final<<<NBATCH, BLOCK, 0, stream>>>(part, out);
}